// Round 4
// baseline (2468.541 us; speedup 1.0000x reference)
//
#include <hip/hip_runtime.h>

#define DIMS 64
#define SCAN_CHUNK 2048  // 256 threads * 8 elems
#define BSHIFT 10        // 1024 rows per bucket
#define BROWS (1 << BSHIFT)
#define NB_MAX 304       // >= ceil(300K/1024)=293
#define STAGE_CAP 16     // staged entries per bucket (flush in groups of 8)
#define PA_BLOCKS 256
#define PA_THREADS 256
#define PB_BLOCKS 64
#define PB_THREADS 512

// ---------------------------------------------------------------------------
// E = concat(U_emb, V_emb), vectorized float4
// ---------------------------------------------------------------------------
__global__ __launch_bounds__(256) void init_e_kernel(
    const float* __restrict__ U, const float* __restrict__ V,
    float* __restrict__ E, int nU_elems, int total_elems) {
  int i = (blockIdx.x * blockDim.x + threadIdx.x) * 4;
  if (i >= total_elems) return;
  float4 v = (i < nU_elems)
      ? *reinterpret_cast<const float4*>(U + i)
      : *reinterpret_cast<const float4*>(V + (i - nU_elems));
  *reinterpret_cast<float4*>(E + i) = v;
}

// ---------------------------------------------------------------------------
// degree histogram (over symmetric rows == node degree)
// ---------------------------------------------------------------------------
__global__ __launch_bounds__(256) void hist_kernel(
    const int* __restrict__ rows, int* __restrict__ cnt, int nnz) {
  int i = blockIdx.x * blockDim.x + threadIdx.x;
  if (i < nnz) atomicAdd(&cnt[rows[i]], 1);
}

// phase1: per-block chunk reduction
__global__ __launch_bounds__(256) void scan_phase1(
    const int* __restrict__ cnt, int* __restrict__ block_sums, int n) {
  __shared__ int sdata[256];
  int base = blockIdx.x * SCAN_CHUNK;
  int sum = 0;
#pragma unroll
  for (int k = 0; k < 8; ++k) {
    int idx = base + k * 256 + threadIdx.x;
    if (idx < n) sum += cnt[idx];
  }
  sdata[threadIdx.x] = sum;
  __syncthreads();
  for (int s = 128; s > 0; s >>= 1) {
    if (threadIdx.x < s) sdata[threadIdx.x] += sdata[threadIdx.x + s];
    __syncthreads();
  }
  if (threadIdx.x == 0) block_sums[blockIdx.x] = sdata[0];
}

// phase2: single 256-wide exclusive scan over block sums; writes row_ptr[n]
__global__ __launch_bounds__(256) void scan_phase2(
    int* __restrict__ block_sums, int n_blocks, int* __restrict__ row_ptr, int n) {
  __shared__ int tmp[256];
  int v = (threadIdx.x < n_blocks) ? block_sums[threadIdx.x] : 0;
  tmp[threadIdx.x] = v;
  __syncthreads();
  for (int offs = 1; offs < 256; offs <<= 1) {
    int t = (threadIdx.x >= offs) ? tmp[threadIdx.x - offs] : 0;
    __syncthreads();
    tmp[threadIdx.x] += t;
    __syncthreads();
  }
  if (threadIdx.x < n_blocks) block_sums[threadIdx.x] = tmp[threadIdx.x] - v;
  if (threadIdx.x == 0) row_ptr[n] = tmp[255];
}

// phase3: per-block chunk scan with offset, writes row_ptr
__global__ __launch_bounds__(256) void scan_phase3(
    const int* __restrict__ cnt, const int* __restrict__ block_sums,
    int* __restrict__ row_ptr, int n) {
  __shared__ int tmp[256];
  __shared__ int s_carry;
  int base = blockIdx.x * SCAN_CHUNK;
  if (threadIdx.x == 0) s_carry = block_sums[blockIdx.x];
  __syncthreads();
#pragma unroll 1
  for (int k = 0; k < 8; ++k) {
    int idx = base + k * 256 + threadIdx.x;
    int v = (idx < n) ? cnt[idx] : 0;
    tmp[threadIdx.x] = v;
    __syncthreads();
    for (int offs = 1; offs < 256; offs <<= 1) {
      int t = (threadIdx.x >= offs) ? tmp[threadIdx.x - offs] : 0;
      __syncthreads();
      tmp[threadIdx.x] += t;
      __syncthreads();
    }
    int incl = tmp[threadIdx.x];
    int carry = s_carry;
    if (idx < n) row_ptr[idx] = carry + incl - v;
    __syncthreads();
    if (threadIdx.x == 0) s_carry = carry + tmp[255];
    __syncthreads();
  }
}

// rs[i] = 1/sqrt(deg[i]); deg==0 -> 1 (matches reference's deg[deg==0]=1)
__global__ __launch_bounds__(256) void rs_kernel(
    const int* __restrict__ cnt, float* __restrict__ rs, int n) {
  int i = blockIdx.x * blockDim.x + threadIdx.x;
  if (i < n) {
    float d = (float)cnt[i];
    rs[i] = (d > 0.0f) ? 1.0f / sqrtf(d) : 1.0f;
  }
}

// bucket bases: 64B-aligned (multiple-of-8 entries) + per-bucket slack
__global__ __launch_bounds__(256) void bucket_init_kernel(
    const int* __restrict__ row_ptr, int* __restrict__ pbase,
    int* __restrict__ gcur, int nb, int slack) {
  int b = blockIdx.x * blockDim.x + threadIdx.x;
  if (b < nb) {
    int p = ((row_ptr[b << BSHIFT] + 7) & ~7) + b * slack;
    pbase[b] = p;
    gcur[b] = p;
  }
}

// ---------------------------------------------------------------------------
// Pass A: LDS-staged multisplit of (row,col) into 293 row-range buckets.
// Every global flush is 8 entries = one full 64B line at an aligned offset
// (all cursor reservations are multiples of 8 from 64B-aligned bases), so
// scatter write traffic ~= payload (85MB) instead of 1 line-event per edge.
// ---------------------------------------------------------------------------
__global__ __launch_bounds__(PA_THREADS) void pass_a_kernel(
    const int* __restrict__ rows, const int* __restrict__ cols,
    int2* __restrict__ temp, int* __restrict__ gcur, int nnz, int nb) {
  __shared__ int2 stage[NB_MAX][STAGE_CAP];
  __shared__ int scnt[NB_MAX];
  for (int b = threadIdx.x; b < nb; b += PA_THREADS) scnt[b] = 0;
  __syncthreads();

  int epb = (nnz + PA_BLOCKS - 1) / PA_BLOCKS;
  int cstart = blockIdx.x * epb;
  int cend = min(nnz, cstart + epb);

  for (int base = cstart; base < cend; base += PA_THREADS) {
    int e = base + threadIdx.x;
    bool done = (e >= cend);
    int r = 0, c = 0, b = 0;
    if (!done) { r = rows[e]; c = cols[e]; b = r >> BSHIFT; }
    for (;;) {
      if (!done) {
        int idx = atomicAdd(&scnt[b], 1);
        if (idx < STAGE_CAP) {
          stage[b][idx] = make_int2(r, c);
          done = true;
        } else {
          atomicAdd(&scnt[b], -1);  // undo failed claim; retry after flush
        }
      }
      __syncthreads();
      // flush full groups of 8 (one thread per bucket)
      for (int bb = threadIdx.x; bb < nb; bb += PA_THREADS) {
        int cval = scnt[bb];
        int n8 = cval & ~7;
        if (n8 > 0) {
          int pos = atomicAdd(&gcur[bb], n8);
          const int4* src = reinterpret_cast<const int4*>(&stage[bb][0]);
          int4* dst = reinterpret_cast<int4*>(&temp[pos]);
#pragma unroll
          for (int k = 0; k < STAGE_CAP / 2; ++k)
            if (k < (n8 >> 1)) dst[k] = src[k];
          for (int k = 0; k < cval - n8; ++k) stage[bb][k] = stage[bb][n8 + k];
          scnt[bb] = cval - n8;
        }
      }
      int pend = __syncthreads_count(done ? 0 : 1);
      if (pend == 0) break;
    }
  }
  // final drain: pad residue to a full aligned group with sentinels (row=-1)
  __syncthreads();
  for (int bb = threadIdx.x; bb < nb; bb += PA_THREADS) {
    int cval = scnt[bb];
    if (cval > 0) {
      int pos = atomicAdd(&gcur[bb], 8);
      for (int k = 0; k < 8; ++k)
        temp[pos + k] = (k < cval) ? stage[bb][k] : make_int2(-1, 0);
    }
  }
}

// ---------------------------------------------------------------------------
// Pass B: per bucket, scatter bucket entries to exact CSR positions.
// Destination window per bucket ~272KB; few persistent blocks/XCD keep the
// windows L2-resident so random 8B writes coalesce before writeback.
// ---------------------------------------------------------------------------
__global__ __launch_bounds__(PB_THREADS) void pass_b_kernel(
    const int2* __restrict__ temp, const int* __restrict__ pbase,
    const int* __restrict__ gcur, const int* __restrict__ row_ptr,
    const float* __restrict__ rs, int2* __restrict__ csr_cv, int nb, int n) {
  __shared__ int ldscur[BROWS];
  for (int b = blockIdx.x; b < nb; b += gridDim.x) {
    int base_row = b << BSHIFT;
    int nrows = min(BROWS, n - base_row);
    for (int r = threadIdx.x; r < nrows; r += PB_THREADS)
      ldscur[r] = row_ptr[base_row + r];
    __syncthreads();
    int start = pbase[b], end = gcur[b];
    for (int i = start + threadIdx.x; i < end; i += PB_THREADS) {
      int2 ent = temp[i];
      if (ent.x >= 0) {
        int p = atomicAdd(&ldscur[ent.x - base_row], 1);
        float val = rs[ent.x] * rs[ent.y];
        csr_cv[p] = make_int2(ent.y, __float_as_int(val));
      }
    }
    __syncthreads();
  }
}

// ---------------------------------------------------------------------------
// SpMM: one wave per row, lane = dim; cur gathers are L3-resident.
// ---------------------------------------------------------------------------
__global__ __launch_bounds__(256) void spmm_kernel(
    const int* __restrict__ row_ptr, const int2* __restrict__ csr_cv,
    const float* __restrict__ cur, float* __restrict__ next, int n_rows) {
  int row  = blockIdx.x * (blockDim.x >> 6) + (threadIdx.x >> 6);
  int lane = threadIdx.x & 63;
  if (row >= n_rows) return;
  int start = row_ptr[row];
  int end   = row_ptr[row + 1];
  float acc = 0.0f;
  int e = start;
  for (; e + 4 <= end; e += 4) {
    int2 e0 = csr_cv[e],     e1 = csr_cv[e + 1];
    int2 e2 = csr_cv[e + 2], e3 = csr_cv[e + 3];
    acc = fmaf(__int_as_float(e0.y), cur[e0.x * DIMS + lane], acc);
    acc = fmaf(__int_as_float(e1.y), cur[e1.x * DIMS + lane], acc);
    acc = fmaf(__int_as_float(e2.y), cur[e2.x * DIMS + lane], acc);
    acc = fmaf(__int_as_float(e3.y), cur[e3.x * DIMS + lane], acc);
  }
  for (; e < end; ++e) {
    int2 ed = csr_cv[e];
    acc = fmaf(__int_as_float(ed.y), cur[ed.x * DIMS + lane], acc);
  }
  next[row * DIMS + lane] = acc;
}

// ---------------------------------------------------------------------------
__global__ __launch_bounds__(256) void gather_kernel(
    const int* __restrict__ u, const int* __restrict__ it,
    const float* __restrict__ cur, float* __restrict__ accU,
    float* __restrict__ accI, int batch, int nU) {
  int b    = blockIdx.x * (blockDim.x >> 6) + (threadIdx.x >> 6);
  int lane = threadIdx.x & 63;
  if (b >= batch) return;
  accU[b * DIMS + lane] += cur[u[b] * DIMS + lane];
  accI[b * DIMS + lane] += cur[(it[b] + nU) * DIMS + lane];
}

__global__ __launch_bounds__(256) void score_kernel(
    const float* __restrict__ accU, const float* __restrict__ accI,
    float* __restrict__ out, int batch) {
  int b    = blockIdx.x * (blockDim.x >> 6) + (threadIdx.x >> 6);
  int lane = threadIdx.x & 63;
  if (b >= batch) return;
  float v = accU[b * DIMS + lane] * accI[b * DIMS + lane];
  for (int offs = 32; offs > 0; offs >>= 1) v += __shfl_down(v, offs, 64);
  if (lane == 0) out[b] = v * (1.0f / 16.0f);
}

// ---------------------------------------------------------------------------
extern "C" void kernel_launch(void* const* d_in, const int* in_sizes, int n_in,
                              void* d_out, int out_size, void* d_ws, size_t ws_size,
                              hipStream_t stream) {
  const int*   u     = (const int*)d_in[0];
  const int*   it    = (const int*)d_in[1];
  const int*   arows = (const int*)d_in[2];
  const int*   acols = (const int*)d_in[3];
  const float* U     = (const float*)d_in[5];
  const float* V     = (const float*)d_in[6];

  const int batch = in_sizes[0];
  const int nnz   = in_sizes[2];
  const int nU    = in_sizes[5] / DIMS;
  const int nV    = in_sizes[6] / DIMS;
  const int N     = nU + nV;
  const int n_scan_blocks = (N + SCAN_CHUNK - 1) / SCAN_CHUNK;
  const int NB    = (N + BROWS - 1) >> BSHIFT;  // 293
  const int slack = PA_BLOCKS * 8 + 8;
  const size_t temp_entries =
      (size_t)((nnz + 7) & ~7) + (size_t)NB * slack + 8;
  const size_t ebytes = (size_t)N * DIMS * 4;
  const size_t xbytes = temp_entries * 8 > ebytes ? temp_entries * 8 : ebytes;

  char*  ws  = (char*)d_ws;
  size_t off = 0;
  auto take = [&](size_t bytes) -> void* {
    void* p = ws + off;
    off = (off + bytes + 255) & ~(size_t)255;
    return p;
  };
  int*   cnt        = (int*)take((size_t)N * 4);
  float* rs         = (float*)take((size_t)N * 4);
  int*   row_ptr    = (int*)take((size_t)(N + 1) * 4);
  int*   block_sums = (int*)take((size_t)256 * 4);
  int*   pbase      = (int*)take((size_t)NB * 4);
  int*   gcur       = (int*)take((size_t)NB * 4);
  int2*  csr_cv     = (int2*)take((size_t)nnz * 8);
  float* bufA       = (float*)take(ebytes);
  char*  X          = (char*)take(xbytes);   // temp (pass A/B), then bufB
  float* accU       = (float*)take((size_t)batch * DIMS * 4);
  float* accI       = (float*)take((size_t)batch * DIMS * 4);
  int2*  temp       = (int2*)X;
  float* bufB       = (float*)X;

  hipMemsetAsync(cnt,  0, (size_t)N * 4, stream);
  hipMemsetAsync(accU, 0, (size_t)batch * DIMS * 4, stream);
  hipMemsetAsync(accI, 0, (size_t)batch * DIMS * 4, stream);

  {
    int total = N * DIMS;
    int t4 = total / 4;
    init_e_kernel<<<(t4 + 255) / 256, 256, 0, stream>>>(U, V, bufA, nU * DIMS, total);
  }

  hist_kernel<<<(nnz + 255) / 256, 256, 0, stream>>>(arows, cnt, nnz);
  scan_phase1<<<n_scan_blocks, 256, 0, stream>>>(cnt, block_sums, N);
  scan_phase2<<<1, 256, 0, stream>>>(block_sums, n_scan_blocks, row_ptr, N);
  scan_phase3<<<n_scan_blocks, 256, 0, stream>>>(cnt, block_sums, row_ptr, N);
  rs_kernel<<<(N + 255) / 256, 256, 0, stream>>>(cnt, rs, N);
  bucket_init_kernel<<<(NB + 255) / 256, 256, 0, stream>>>(row_ptr, pbase, gcur, NB, slack);
  pass_a_kernel<<<PA_BLOCKS, PA_THREADS, 0, stream>>>(arows, acols, temp, gcur, nnz, NB);
  pass_b_kernel<<<PB_BLOCKS, PB_THREADS, 0, stream>>>(temp, pbase, gcur, row_ptr, rs,
                                                      csr_cv, NB, N);

  // E0 contribution to the batch accumulators
  gather_kernel<<<(batch + 3) / 4, 256, 0, stream>>>(u, it, bufA, accU, accI, batch, nU);

  float* cur = bufA;
  float* nxt = bufB;
  for (int layer = 0; layer < 3; ++layer) {
    spmm_kernel<<<(N + 3) / 4, 256, 0, stream>>>(row_ptr, csr_cv, cur, nxt, N);
    gather_kernel<<<(batch + 3) / 4, 256, 0, stream>>>(u, it, nxt, accU, accI, batch, nU);
    float* t = cur; cur = nxt; nxt = t;
  }

  score_kernel<<<(batch + 3) / 4, 256, 0, stream>>>(accU, accI, (float*)d_out, batch);
}

// Round 5
// 2208.062 us; speedup vs baseline: 1.1180x; 1.1180x over previous
//
#include <hip/hip_runtime.h>

#define DIMS 64
#define SCAN_CHUNK 2048  // 256 threads * 8 elems
#define BSHIFT 10        // 1024 rows per bucket
#define BROWS (1 << BSHIFT)
#define NB_MAX 304       // >= ceil(300K/1024)=293
#define SCAP 24          // staged entries per bucket; flush groups of 16 (64B)
#define SPITCH 25        // odd pitch -> bank-conflict-free across buckets
#define PA_BLOCKS 1280   // 5 blocks/CU (LDS ~31.6KB/block)
#define PA_THREADS 256
#define PB_BLOCKS 128
#define PB_THREADS 512
#define SENTINEL 0xFFFFFFFFu

// ---------------------------------------------------------------------------
// E = concat(U_emb, V_emb), vectorized float4
// ---------------------------------------------------------------------------
__global__ __launch_bounds__(256) void init_e_kernel(
    const float* __restrict__ U, const float* __restrict__ V,
    float* __restrict__ E, int nU_elems, int total_elems) {
  int i = (blockIdx.x * blockDim.x + threadIdx.x) * 4;
  if (i >= total_elems) return;
  float4 v = (i < nU_elems)
      ? *reinterpret_cast<const float4*>(U + i)
      : *reinterpret_cast<const float4*>(V + (i - nU_elems));
  *reinterpret_cast<float4*>(E + i) = v;
}

// ---------------------------------------------------------------------------
// degree histogram
// ---------------------------------------------------------------------------
__global__ __launch_bounds__(256) void hist_kernel(
    const int* __restrict__ rows, int* __restrict__ cnt, int nnz) {
  int i = blockIdx.x * blockDim.x + threadIdx.x;
  if (i < nnz) atomicAdd(&cnt[rows[i]], 1);
}

// phase1: per-block chunk reduction
__global__ __launch_bounds__(256) void scan_phase1(
    const int* __restrict__ cnt, int* __restrict__ block_sums, int n) {
  __shared__ int sdata[256];
  int base = blockIdx.x * SCAN_CHUNK;
  int sum = 0;
#pragma unroll
  for (int k = 0; k < 8; ++k) {
    int idx = base + k * 256 + threadIdx.x;
    if (idx < n) sum += cnt[idx];
  }
  sdata[threadIdx.x] = sum;
  __syncthreads();
  for (int s = 128; s > 0; s >>= 1) {
    if (threadIdx.x < s) sdata[threadIdx.x] += sdata[threadIdx.x + s];
    __syncthreads();
  }
  if (threadIdx.x == 0) block_sums[blockIdx.x] = sdata[0];
}

// phase2: single 256-wide exclusive scan over block sums; writes row_ptr[n]
__global__ __launch_bounds__(256) void scan_phase2(
    int* __restrict__ block_sums, int n_blocks, int* __restrict__ row_ptr, int n) {
  __shared__ int tmp[256];
  int v = (threadIdx.x < n_blocks) ? block_sums[threadIdx.x] : 0;
  tmp[threadIdx.x] = v;
  __syncthreads();
  for (int offs = 1; offs < 256; offs <<= 1) {
    int t = (threadIdx.x >= offs) ? tmp[threadIdx.x - offs] : 0;
    __syncthreads();
    tmp[threadIdx.x] += t;
    __syncthreads();
  }
  if (threadIdx.x < n_blocks) block_sums[threadIdx.x] = tmp[threadIdx.x] - v;
  if (threadIdx.x == 0) row_ptr[n] = tmp[255];
}

// phase3: per-block chunk scan with offset, writes row_ptr
__global__ __launch_bounds__(256) void scan_phase3(
    const int* __restrict__ cnt, const int* __restrict__ block_sums,
    int* __restrict__ row_ptr, int n) {
  __shared__ int tmp[256];
  __shared__ int s_carry;
  int base = blockIdx.x * SCAN_CHUNK;
  if (threadIdx.x == 0) s_carry = block_sums[blockIdx.x];
  __syncthreads();
#pragma unroll 1
  for (int k = 0; k < 8; ++k) {
    int idx = base + k * 256 + threadIdx.x;
    int v = (idx < n) ? cnt[idx] : 0;
    tmp[threadIdx.x] = v;
    __syncthreads();
    for (int offs = 1; offs < 256; offs <<= 1) {
      int t = (threadIdx.x >= offs) ? tmp[threadIdx.x - offs] : 0;
      __syncthreads();
      tmp[threadIdx.x] += t;
      __syncthreads();
    }
    int incl = tmp[threadIdx.x];
    int carry = s_carry;
    if (idx < n) row_ptr[idx] = carry + incl - v;
    __syncthreads();
    if (threadIdx.x == 0) s_carry = carry + tmp[255];
    __syncthreads();
  }
}

// rs[i] = 1/sqrt(deg[i]); deg==0 -> 1
__global__ __launch_bounds__(256) void rs_kernel(
    const int* __restrict__ cnt, float* __restrict__ rs, int n) {
  int i = blockIdx.x * blockDim.x + threadIdx.x;
  if (i < n) {
    float d = (float)cnt[i];
    rs[i] = (d > 0.0f) ? 1.0f / sqrtf(d) : 1.0f;
  }
}

// bucket bases: 64B-aligned (multiple-of-16 4B entries) + per-bucket slack
__global__ __launch_bounds__(256) void bucket_init_kernel(
    const int* __restrict__ row_ptr, int* __restrict__ pbase,
    int* __restrict__ gcur, int nb, int slack) {
  int b = blockIdx.x * blockDim.x + threadIdx.x;
  if (b < nb) {
    int p = ((row_ptr[b << BSHIFT] + 15) & ~15) + b * slack;
    pbase[b] = p;
    gcur[b] = p;
  }
}

// ---------------------------------------------------------------------------
// Pass A: LDS-staged multisplit of packed (row_low<<19 | col) 4B entries into
// 293 row-range buckets. Flush quantum = 16 entries = one full 64B line at an
// aligned offset; odd LDS pitch (25) kills cross-bucket bank conflicts.
// ---------------------------------------------------------------------------
__global__ __launch_bounds__(PA_THREADS) void pass_a_kernel(
    const int* __restrict__ rows, const int* __restrict__ cols,
    unsigned* __restrict__ temp, int* __restrict__ gcur, int nnz, int nb) {
  __shared__ unsigned stage[NB_MAX * SPITCH];
  __shared__ int scnt[NB_MAX];
  for (int b = threadIdx.x; b < nb; b += PA_THREADS) scnt[b] = 0;
  __syncthreads();

  int epb = (nnz + PA_BLOCKS - 1) / PA_BLOCKS;
  int cstart = blockIdx.x * epb;
  int cend = min(nnz, cstart + epb);

  for (int base = cstart; base < cend; base += PA_THREADS) {
    int e = base + threadIdx.x;
    bool done = (e >= cend);
    unsigned packed = 0;
    int b = 0;
    if (!done) {
      int r = rows[e];
      int c = cols[e];
      b = r >> BSHIFT;
      packed = ((unsigned)(r & (BROWS - 1)) << 19) | (unsigned)c;
    }
    for (;;) {
      if (!done) {
        int idx = atomicAdd(&scnt[b], 1);
        if (idx < SCAP) {
          stage[b * SPITCH + idx] = packed;
          done = true;
        } else {
          atomicAdd(&scnt[b], -1);  // undo failed claim; retry after flush
        }
      }
      __syncthreads();
      // flush full 16-groups (one thread per bucket, conflict-free pitch)
      for (int bb = threadIdx.x; bb < nb; bb += PA_THREADS) {
        int cval = scnt[bb];
        if (cval >= 16) {
          int pos = atomicAdd(&gcur[bb], 16);
          unsigned v[16];
#pragma unroll
          for (int k = 0; k < 16; ++k) v[k] = stage[bb * SPITCH + k];
          uint4* dst = reinterpret_cast<uint4*>(&temp[pos]);
          dst[0] = make_uint4(v[0], v[1], v[2], v[3]);
          dst[1] = make_uint4(v[4], v[5], v[6], v[7]);
          dst[2] = make_uint4(v[8], v[9], v[10], v[11]);
          dst[3] = make_uint4(v[12], v[13], v[14], v[15]);
          for (int k = 0; k < cval - 16; ++k)
            stage[bb * SPITCH + k] = stage[bb * SPITCH + 16 + k];
          scnt[bb] = cval - 16;
        }
      }
      int pend = __syncthreads_count(done ? 0 : 1);
      if (pend == 0) break;
    }
  }
  // final drain: pad residue to a full aligned 16-group with sentinels
  __syncthreads();
  for (int bb = threadIdx.x; bb < nb; bb += PA_THREADS) {
    int cval = scnt[bb];
    if (cval > 0) {
      int pos = atomicAdd(&gcur[bb], 16);
      for (int k = 0; k < 16; ++k)
        temp[pos + k] = (k < cval) ? stage[bb * SPITCH + k] : SENTINEL;
    }
  }
}

// ---------------------------------------------------------------------------
// Pass B: per bucket, scatter bucket entries to exact CSR positions.
// Destination window per bucket ~272KB; concurrent windows ~4MB/XCD stay
// mostly L2-resident so random 8B writes coalesce before writeback.
// ---------------------------------------------------------------------------
__global__ __launch_bounds__(PB_THREADS) void pass_b_kernel(
    const unsigned* __restrict__ temp, const int* __restrict__ pbase,
    const int* __restrict__ gcur, const int* __restrict__ row_ptr,
    const float* __restrict__ rs, int2* __restrict__ csr_cv, int nb, int n) {
  __shared__ int ldscur[BROWS];
  for (int b = blockIdx.x; b < nb; b += gridDim.x) {
    int base_row = b << BSHIFT;
    int nrows = min(BROWS, n - base_row);
    for (int r = threadIdx.x; r < nrows; r += PB_THREADS)
      ldscur[r] = row_ptr[base_row + r];
    __syncthreads();
    int start = pbase[b], end = gcur[b];
    for (int i = start + threadIdx.x; i < end; i += PB_THREADS) {
      unsigned ent = temp[i];
      if (ent != SENTINEL) {
        int col = (int)(ent & 0x7FFFFu);
        int rlow = (int)(ent >> 19);
        int p = atomicAdd(&ldscur[rlow], 1);
        float val = rs[base_row + rlow] * rs[col];
        csr_cv[p] = make_int2(col, __float_as_int(val));
      }
    }
    __syncthreads();
  }
}

// ---------------------------------------------------------------------------
// SpMM: one wave per row, lane = dim; cur gathers are L3-resident.
// ---------------------------------------------------------------------------
__global__ __launch_bounds__(256) void spmm_kernel(
    const int* __restrict__ row_ptr, const int2* __restrict__ csr_cv,
    const float* __restrict__ cur, float* __restrict__ next, int n_rows) {
  int row  = blockIdx.x * (blockDim.x >> 6) + (threadIdx.x >> 6);
  int lane = threadIdx.x & 63;
  if (row >= n_rows) return;
  int start = row_ptr[row];
  int end   = row_ptr[row + 1];
  float acc = 0.0f;
  int e = start;
  for (; e + 4 <= end; e += 4) {
    int2 e0 = csr_cv[e],     e1 = csr_cv[e + 1];
    int2 e2 = csr_cv[e + 2], e3 = csr_cv[e + 3];
    acc = fmaf(__int_as_float(e0.y), cur[e0.x * DIMS + lane], acc);
    acc = fmaf(__int_as_float(e1.y), cur[e1.x * DIMS + lane], acc);
    acc = fmaf(__int_as_float(e2.y), cur[e2.x * DIMS + lane], acc);
    acc = fmaf(__int_as_float(e3.y), cur[e3.x * DIMS + lane], acc);
  }
  for (; e < end; ++e) {
    int2 ed = csr_cv[e];
    acc = fmaf(__int_as_float(ed.y), cur[ed.x * DIMS + lane], acc);
  }
  next[row * DIMS + lane] = acc;
}

// ---------------------------------------------------------------------------
__global__ __launch_bounds__(256) void gather_kernel(
    const int* __restrict__ u, const int* __restrict__ it,
    const float* __restrict__ cur, float* __restrict__ accU,
    float* __restrict__ accI, int batch, int nU) {
  int b    = blockIdx.x * (blockDim.x >> 6) + (threadIdx.x >> 6);
  int lane = threadIdx.x & 63;
  if (b >= batch) return;
  accU[b * DIMS + lane] += cur[u[b] * DIMS + lane];
  accI[b * DIMS + lane] += cur[(it[b] + nU) * DIMS + lane];
}

__global__ __launch_bounds__(256) void score_kernel(
    const float* __restrict__ accU, const float* __restrict__ accI,
    float* __restrict__ out, int batch) {
  int b    = blockIdx.x * (blockDim.x >> 6) + (threadIdx.x >> 6);
  int lane = threadIdx.x & 63;
  if (b >= batch) return;
  float v = accU[b * DIMS + lane] * accI[b * DIMS + lane];
  for (int offs = 32; offs > 0; offs >>= 1) v += __shfl_down(v, offs, 64);
  if (lane == 0) out[b] = v * (1.0f / 16.0f);
}

// ---------------------------------------------------------------------------
extern "C" void kernel_launch(void* const* d_in, const int* in_sizes, int n_in,
                              void* d_out, int out_size, void* d_ws, size_t ws_size,
                              hipStream_t stream) {
  const int*   u     = (const int*)d_in[0];
  const int*   it    = (const int*)d_in[1];
  const int*   arows = (const int*)d_in[2];
  const int*   acols = (const int*)d_in[3];
  const float* U     = (const float*)d_in[5];
  const float* V     = (const float*)d_in[6];

  const int batch = in_sizes[0];
  const int nnz   = in_sizes[2];
  const int nU    = in_sizes[5] / DIMS;
  const int nV    = in_sizes[6] / DIMS;
  const int N     = nU + nV;
  const int n_scan_blocks = (N + SCAN_CHUNK - 1) / SCAN_CHUNK;
  const int NB    = (N + BROWS - 1) >> BSHIFT;  // 293
  const int slack = PA_BLOCKS * 16 + 16;        // worst-case drain pads
  const size_t temp_entries =
      (size_t)((nnz + 15) & ~15) + (size_t)NB * slack + 16;
  const size_t ebytes = (size_t)N * DIMS * 4;
  const size_t tbytes = temp_entries * 4;
  const size_t xbytes = tbytes > ebytes ? tbytes : ebytes;

  char*  ws  = (char*)d_ws;
  size_t off = 0;
  auto take = [&](size_t bytes) -> void* {
    void* p = ws + off;
    off = (off + bytes + 255) & ~(size_t)255;
    return p;
  };
  int*     cnt        = (int*)take((size_t)N * 4);
  float*   rs         = (float*)take((size_t)N * 4);
  int*     row_ptr    = (int*)take((size_t)(N + 1) * 4);
  int*     block_sums = (int*)take((size_t)256 * 4);
  int*     pbase      = (int*)take((size_t)NB * 4);
  int*     gcur       = (int*)take((size_t)NB * 4);
  int2*    csr_cv     = (int2*)take((size_t)nnz * 8);
  char*    X          = (char*)take(xbytes);   // temp (build), then bufA (E)
  float*   bufB       = (float*)take(ebytes);
  float*   accU       = (float*)take((size_t)batch * DIMS * 4);
  float*   accI       = (float*)take((size_t)batch * DIMS * 4);
  unsigned* temp      = (unsigned*)X;
  float*   bufA       = (float*)X;

  hipMemsetAsync(cnt,  0, (size_t)N * 4, stream);
  hipMemsetAsync(accU, 0, (size_t)batch * DIMS * 4, stream);
  hipMemsetAsync(accI, 0, (size_t)batch * DIMS * 4, stream);

  // ---- CSR build (uses X as temp) ----
  hist_kernel<<<(nnz + 255) / 256, 256, 0, stream>>>(arows, cnt, nnz);
  scan_phase1<<<n_scan_blocks, 256, 0, stream>>>(cnt, block_sums, N);
  scan_phase2<<<1, 256, 0, stream>>>(block_sums, n_scan_blocks, row_ptr, N);
  scan_phase3<<<n_scan_blocks, 256, 0, stream>>>(cnt, block_sums, row_ptr, N);
  rs_kernel<<<(N + 255) / 256, 256, 0, stream>>>(cnt, rs, N);
  bucket_init_kernel<<<(NB + 255) / 256, 256, 0, stream>>>(row_ptr, pbase, gcur, NB, slack);
  pass_a_kernel<<<PA_BLOCKS, PA_THREADS, 0, stream>>>(arows, acols, temp, gcur, nnz, NB);
  pass_b_kernel<<<PB_BLOCKS, PB_THREADS, 0, stream>>>(temp, pbase, gcur, row_ptr, rs,
                                                      csr_cv, NB, N);

  // ---- E0 init (X becomes bufA now that temp is dead) ----
  {
    int total = N * DIMS;
    int t4 = total / 4;
    init_e_kernel<<<(t4 + 255) / 256, 256, 0, stream>>>(U, V, bufA, nU * DIMS, total);
  }
  gather_kernel<<<(batch + 3) / 4, 256, 0, stream>>>(u, it, bufA, accU, accI, batch, nU);

  float* cur = bufA;
  float* nxt = bufB;
  for (int layer = 0; layer < 3; ++layer) {
    spmm_kernel<<<(N + 3) / 4, 256, 0, stream>>>(row_ptr, csr_cv, cur, nxt, N);
    gather_kernel<<<(batch + 3) / 4, 256, 0, stream>>>(u, it, nxt, accU, accI, batch, nU);
    float* t = cur; cur = nxt; nxt = t;
  }

  score_kernel<<<(batch + 3) / 4, 256, 0, stream>>>(accU, accI, (float*)d_out, batch);
}

// Round 6
// 1852.612 us; speedup vs baseline: 1.3325x; 1.1919x over previous
//
#include <hip/hip_runtime.h>

#define DIMS 64
#define SCAN_CHUNK 2048  // 256 threads * 8 elems
#define BSHIFT 10        // 1024 rows per bucket
#define BROWS (1 << BSHIFT)
#define NB_MAX 304       // >= ceil(300K/1024)=293
#define BCAP 65536       // fixed bucket capacity (mean ~34K + drain pads <54K)
#define SCAP 24          // staged entries per bucket; flush groups of 16 (64B)
#define SPITCH 25        // odd pitch -> bank-conflict-free across buckets
#define PA_BLOCKS 1280   // 5 blocks/CU (LDS ~31.6KB/block)
#define PA_THREADS 256
#define PB_BLOCKS 128
#define PB_THREADS 512
#define SENTINEL 0xFFFFFFFFu

// ---------------------------------------------------------------------------
// E = concat(U_emb, V_emb), vectorized float4
// ---------------------------------------------------------------------------
__global__ __launch_bounds__(256) void init_e_kernel(
    const float* __restrict__ U, const float* __restrict__ V,
    float* __restrict__ E, int nU_elems, int total_elems) {
  int i = (blockIdx.x * blockDim.x + threadIdx.x) * 4;
  if (i >= total_elems) return;
  float4 v = (i < nU_elems)
      ? *reinterpret_cast<const float4*>(U + i)
      : *reinterpret_cast<const float4*>(V + (i - nU_elems));
  *reinterpret_cast<float4*>(E + i) = v;
}

// ---------------------------------------------------------------------------
// Pass A: LDS-staged multisplit of packed (row_low<<19 | col) 4B entries into
// fixed-capacity row-range buckets (base = b*BCAP, no row_ptr dependency).
// Flush quantum = 16 entries = one full 64B line at an aligned offset.
// ---------------------------------------------------------------------------
__global__ __launch_bounds__(PA_THREADS) void pass_a_kernel(
    const int* __restrict__ rows, const int* __restrict__ cols,
    unsigned* __restrict__ temp, int* __restrict__ gcur, int nnz, int nb) {
  __shared__ unsigned stage[NB_MAX * SPITCH];
  __shared__ int scnt[NB_MAX];
  for (int b = threadIdx.x; b < nb; b += PA_THREADS) scnt[b] = 0;
  __syncthreads();

  int epb = (nnz + PA_BLOCKS - 1) / PA_BLOCKS;
  int cstart = blockIdx.x * epb;
  int cend = min(nnz, cstart + epb);

  for (int base = cstart; base < cend; base += PA_THREADS) {
    int e = base + threadIdx.x;
    bool done = (e >= cend);
    unsigned packed = 0;
    int b = 0;
    if (!done) {
      int r = rows[e];
      int c = cols[e];
      b = r >> BSHIFT;
      packed = ((unsigned)(r & (BROWS - 1)) << 19) | (unsigned)c;
    }
    for (;;) {
      if (!done) {
        int idx = atomicAdd(&scnt[b], 1);
        if (idx < SCAP) {
          stage[b * SPITCH + idx] = packed;
          done = true;
        } else {
          atomicAdd(&scnt[b], -1);  // undo failed claim; retry after flush
        }
      }
      __syncthreads();
      // flush full 16-groups (one thread per bucket, conflict-free pitch)
      for (int bb = threadIdx.x; bb < nb; bb += PA_THREADS) {
        int cval = scnt[bb];
        if (cval >= 16) {
          int pos = atomicAdd(&gcur[bb], 16);
          unsigned v[16];
#pragma unroll
          for (int k = 0; k < 16; ++k) v[k] = stage[bb * SPITCH + k];
          uint4* dst = reinterpret_cast<uint4*>(&temp[pos]);
          dst[0] = make_uint4(v[0], v[1], v[2], v[3]);
          dst[1] = make_uint4(v[4], v[5], v[6], v[7]);
          dst[2] = make_uint4(v[8], v[9], v[10], v[11]);
          dst[3] = make_uint4(v[12], v[13], v[14], v[15]);
          for (int k = 0; k < cval - 16; ++k)
            stage[bb * SPITCH + k] = stage[bb * SPITCH + 16 + k];
          scnt[bb] = cval - 16;
        }
      }
      int pend = __syncthreads_count(done ? 0 : 1);
      if (pend == 0) break;
    }
  }
  // final drain: pad residue to a full aligned 16-group with sentinels
  __syncthreads();
  for (int bb = threadIdx.x; bb < nb; bb += PA_THREADS) {
    int cval = scnt[bb];
    if (cval > 0) {
      int pos = atomicAdd(&gcur[bb], 16);
      for (int k = 0; k < 16; ++k)
        temp[pos + k] = (k < cval) ? stage[bb * SPITCH + k] : SENTINEL;
    }
  }
}

// ---------------------------------------------------------------------------
// Per-bucket histogram: LDS atomics + coalesced contiguous cnt stores.
// Replaces the global-atomic hist (312MB of line-granular write events).
// ---------------------------------------------------------------------------
__global__ __launch_bounds__(512) void hist_bucket_kernel(
    const unsigned* __restrict__ temp, const int* __restrict__ gcur,
    int* __restrict__ cnt, int n) {
  __shared__ int lcnt[BROWS];
  int b = blockIdx.x;
  int base_row = b << BSHIFT;
  int nrows = min(BROWS, n - base_row);
  for (int r = threadIdx.x; r < BROWS; r += 512) lcnt[r] = 0;
  __syncthreads();
  int start = b * BCAP, end = gcur[b];
  for (int i = start + threadIdx.x; i < end; i += 512) {
    unsigned ent = temp[i];
    if (ent != SENTINEL) atomicAdd(&lcnt[ent >> 19], 1);
  }
  __syncthreads();
  for (int r = threadIdx.x; r < nrows; r += 512)
    cnt[base_row + r] = lcnt[r];
}

// phase1: per-block chunk reduction
__global__ __launch_bounds__(256) void scan_phase1(
    const int* __restrict__ cnt, int* __restrict__ block_sums, int n) {
  __shared__ int sdata[256];
  int base = blockIdx.x * SCAN_CHUNK;
  int sum = 0;
#pragma unroll
  for (int k = 0; k < 8; ++k) {
    int idx = base + k * 256 + threadIdx.x;
    if (idx < n) sum += cnt[idx];
  }
  sdata[threadIdx.x] = sum;
  __syncthreads();
  for (int s = 128; s > 0; s >>= 1) {
    if (threadIdx.x < s) sdata[threadIdx.x] += sdata[threadIdx.x + s];
    __syncthreads();
  }
  if (threadIdx.x == 0) block_sums[blockIdx.x] = sdata[0];
}

// phase2: single 256-wide exclusive scan over block sums; writes row_ptr[n]
__global__ __launch_bounds__(256) void scan_phase2(
    int* __restrict__ block_sums, int n_blocks, int* __restrict__ row_ptr, int n) {
  __shared__ int tmp[256];
  int v = (threadIdx.x < n_blocks) ? block_sums[threadIdx.x] : 0;
  tmp[threadIdx.x] = v;
  __syncthreads();
  for (int offs = 1; offs < 256; offs <<= 1) {
    int t = (threadIdx.x >= offs) ? tmp[threadIdx.x - offs] : 0;
    __syncthreads();
    tmp[threadIdx.x] += t;
    __syncthreads();
  }
  if (threadIdx.x < n_blocks) block_sums[threadIdx.x] = tmp[threadIdx.x] - v;
  if (threadIdx.x == 0) row_ptr[n] = tmp[255];
}

// phase3: per-block chunk scan with offset, writes row_ptr
__global__ __launch_bounds__(256) void scan_phase3(
    const int* __restrict__ cnt, const int* __restrict__ block_sums,
    int* __restrict__ row_ptr, int n) {
  __shared__ int tmp[256];
  __shared__ int s_carry;
  int base = blockIdx.x * SCAN_CHUNK;
  if (threadIdx.x == 0) s_carry = block_sums[blockIdx.x];
  __syncthreads();
#pragma unroll 1
  for (int k = 0; k < 8; ++k) {
    int idx = base + k * 256 + threadIdx.x;
    int v = (idx < n) ? cnt[idx] : 0;
    tmp[threadIdx.x] = v;
    __syncthreads();
    for (int offs = 1; offs < 256; offs <<= 1) {
      int t = (threadIdx.x >= offs) ? tmp[threadIdx.x - offs] : 0;
      __syncthreads();
      tmp[threadIdx.x] += t;
      __syncthreads();
    }
    int incl = tmp[threadIdx.x];
    int carry = s_carry;
    if (idx < n) row_ptr[idx] = carry + incl - v;
    __syncthreads();
    if (threadIdx.x == 0) s_carry = carry + tmp[255];
    __syncthreads();
  }
}

// rs[i] = 1/sqrt(deg[i]); deg==0 -> 1
__global__ __launch_bounds__(256) void rs_kernel(
    const int* __restrict__ cnt, float* __restrict__ rs, int n) {
  int i = blockIdx.x * blockDim.x + threadIdx.x;
  if (i < n) {
    float d = (float)cnt[i];
    rs[i] = (d > 0.0f) ? 1.0f / sqrtf(d) : 1.0f;
  }
}

// gcur init for fixed-capacity buckets
__global__ __launch_bounds__(256) void bucket_init_kernel(
    int* __restrict__ gcur, int nb) {
  int b = blockIdx.x * blockDim.x + threadIdx.x;
  if (b < nb) gcur[b] = b * BCAP;
}

// ---------------------------------------------------------------------------
// Pass B: per bucket, scatter bucket entries to exact CSR positions.
// Destination window per bucket ~272KB; concurrent windows stay mostly
// L2-resident so random 8B writes coalesce before writeback.
// ---------------------------------------------------------------------------
__global__ __launch_bounds__(PB_THREADS) void pass_b_kernel(
    const unsigned* __restrict__ temp, const int* __restrict__ gcur,
    const int* __restrict__ row_ptr, const float* __restrict__ rs,
    int2* __restrict__ csr_cv, int nb, int n) {
  __shared__ int ldscur[BROWS];
  for (int b = blockIdx.x; b < nb; b += gridDim.x) {
    int base_row = b << BSHIFT;
    int nrows = min(BROWS, n - base_row);
    for (int r = threadIdx.x; r < nrows; r += PB_THREADS)
      ldscur[r] = row_ptr[base_row + r];
    __syncthreads();
    int start = b * BCAP, end = gcur[b];
    for (int i = start + threadIdx.x; i < end; i += PB_THREADS) {
      unsigned ent = temp[i];
      if (ent != SENTINEL) {
        int col = (int)(ent & 0x7FFFFu);
        int rlow = (int)(ent >> 19);
        int p = atomicAdd(&ldscur[rlow], 1);
        float val = rs[base_row + rlow] * rs[col];
        csr_cv[p] = make_int2(col, __float_as_int(val));
      }
    }
    __syncthreads();
  }
}

// ---------------------------------------------------------------------------
// SpMM: one wave per row, lane = dim; cur gathers are L3-resident.
// ---------------------------------------------------------------------------
__global__ __launch_bounds__(256) void spmm_kernel(
    const int* __restrict__ row_ptr, const int2* __restrict__ csr_cv,
    const float* __restrict__ cur, float* __restrict__ next, int n_rows) {
  int row  = blockIdx.x * (blockDim.x >> 6) + (threadIdx.x >> 6);
  int lane = threadIdx.x & 63;
  if (row >= n_rows) return;
  int start = row_ptr[row];
  int end   = row_ptr[row + 1];
  float acc = 0.0f;
  int e = start;
  for (; e + 4 <= end; e += 4) {
    int2 e0 = csr_cv[e],     e1 = csr_cv[e + 1];
    int2 e2 = csr_cv[e + 2], e3 = csr_cv[e + 3];
    acc = fmaf(__int_as_float(e0.y), cur[e0.x * DIMS + lane], acc);
    acc = fmaf(__int_as_float(e1.y), cur[e1.x * DIMS + lane], acc);
    acc = fmaf(__int_as_float(e2.y), cur[e2.x * DIMS + lane], acc);
    acc = fmaf(__int_as_float(e3.y), cur[e3.x * DIMS + lane], acc);
  }
  for (; e < end; ++e) {
    int2 ed = csr_cv[e];
    acc = fmaf(__int_as_float(ed.y), cur[ed.x * DIMS + lane], acc);
  }
  next[row * DIMS + lane] = acc;
}

// ---------------------------------------------------------------------------
__global__ __launch_bounds__(256) void gather_kernel(
    const int* __restrict__ u, const int* __restrict__ it,
    const float* __restrict__ cur, float* __restrict__ accU,
    float* __restrict__ accI, int batch, int nU) {
  int b    = blockIdx.x * (blockDim.x >> 6) + (threadIdx.x >> 6);
  int lane = threadIdx.x & 63;
  if (b >= batch) return;
  accU[b * DIMS + lane] += cur[u[b] * DIMS + lane];
  accI[b * DIMS + lane] += cur[(it[b] + nU) * DIMS + lane];
}

__global__ __launch_bounds__(256) void score_kernel(
    const float* __restrict__ accU, const float* __restrict__ accI,
    float* __restrict__ out, int batch) {
  int b    = blockIdx.x * (blockDim.x >> 6) + (threadIdx.x >> 6);
  int lane = threadIdx.x & 63;
  if (b >= batch) return;
  float v = accU[b * DIMS + lane] * accI[b * DIMS + lane];
  for (int offs = 32; offs > 0; offs >>= 1) v += __shfl_down(v, offs, 64);
  if (lane == 0) out[b] = v * (1.0f / 16.0f);
}

// ---------------------------------------------------------------------------
extern "C" void kernel_launch(void* const* d_in, const int* in_sizes, int n_in,
                              void* d_out, int out_size, void* d_ws, size_t ws_size,
                              hipStream_t stream) {
  const int*   u     = (const int*)d_in[0];
  const int*   it    = (const int*)d_in[1];
  const int*   arows = (const int*)d_in[2];
  const int*   acols = (const int*)d_in[3];
  const float* U     = (const float*)d_in[5];
  const float* V     = (const float*)d_in[6];

  const int batch = in_sizes[0];
  const int nnz   = in_sizes[2];
  const int nU    = in_sizes[5] / DIMS;
  const int nV    = in_sizes[6] / DIMS;
  const int N     = nU + nV;
  const int n_scan_blocks = (N + SCAN_CHUNK - 1) / SCAN_CHUNK;
  const int NB    = (N + BROWS - 1) >> BSHIFT;  // 293
  const size_t ebytes = (size_t)N * DIMS * 4;
  const size_t tbytes = (size_t)NB * BCAP * 4;
  const size_t xbytes = tbytes > ebytes ? tbytes : ebytes;

  char*  ws  = (char*)d_ws;
  size_t off = 0;
  auto take = [&](size_t bytes) -> void* {
    void* p = ws + off;
    off = (off + bytes + 255) & ~(size_t)255;
    return p;
  };
  int*     cnt        = (int*)take((size_t)N * 4);
  float*   rs         = (float*)take((size_t)N * 4);
  int*     row_ptr    = (int*)take((size_t)(N + 1) * 4);
  int*     block_sums = (int*)take((size_t)256 * 4);
  int*     gcur       = (int*)take((size_t)NB * 4);
  int2*    csr_cv     = (int2*)take((size_t)nnz * 8);
  char*    X          = (char*)take(xbytes);   // temp (build), then bufA (E)
  float*   bufB       = (float*)take(ebytes);
  float*   accU       = (float*)take((size_t)batch * DIMS * 4);
  float*   accI       = (float*)take((size_t)batch * DIMS * 4);
  unsigned* temp      = (unsigned*)X;
  float*   bufA       = (float*)X;

  hipMemsetAsync(accU, 0, (size_t)batch * DIMS * 4, stream);
  hipMemsetAsync(accI, 0, (size_t)batch * DIMS * 4, stream);

  // ---- CSR build (uses X as temp) ----
  bucket_init_kernel<<<(NB + 255) / 256, 256, 0, stream>>>(gcur, NB);
  pass_a_kernel<<<PA_BLOCKS, PA_THREADS, 0, stream>>>(arows, acols, temp, gcur, nnz, NB);
  hist_bucket_kernel<<<NB, 512, 0, stream>>>(temp, gcur, cnt, N);
  scan_phase1<<<n_scan_blocks, 256, 0, stream>>>(cnt, block_sums, N);
  scan_phase2<<<1, 256, 0, stream>>>(block_sums, n_scan_blocks, row_ptr, N);
  scan_phase3<<<n_scan_blocks, 256, 0, stream>>>(cnt, block_sums, row_ptr, N);
  rs_kernel<<<(N + 255) / 256, 256, 0, stream>>>(cnt, rs, N);
  pass_b_kernel<<<PB_BLOCKS, PB_THREADS, 0, stream>>>(temp, gcur, row_ptr, rs,
                                                      csr_cv, NB, N);

  // ---- E0 init (X becomes bufA now that temp is dead) ----
  {
    int total = N * DIMS;
    int t4 = total / 4;
    init_e_kernel<<<(t4 + 255) / 256, 256, 0, stream>>>(U, V, bufA, nU * DIMS, total);
  }
  gather_kernel<<<(batch + 3) / 4, 256, 0, stream>>>(u, it, bufA, accU, accI, batch, nU);

  float* cur = bufA;
  float* nxt = bufB;
  for (int layer = 0; layer < 3; ++layer) {
    spmm_kernel<<<(N + 3) / 4, 256, 0, stream>>>(row_ptr, csr_cv, cur, nxt, N);
    gather_kernel<<<(batch + 3) / 4, 256, 0, stream>>>(u, it, nxt, accU, accI, batch, nU);
    float* t = cur; cur = nxt; nxt = t;
  }

  score_kernel<<<(batch + 3) / 4, 256, 0, stream>>>(accU, accI, (float*)d_out, batch);
}

// Round 7
// 1810.315 us; speedup vs baseline: 1.3636x; 1.0234x over previous
//
#include <hip/hip_runtime.h>

#define DIMS 64
#define SCAN_CHUNK 2048  // 256 threads * 8 elems
#define BSHIFT 10        // 1024 rows per bucket
#define BROWS (1 << BSHIFT)
#define NB_MAX 304       // >= ceil(300K/1024)=293
#define BCAP 65536       // fixed bucket capacity (mean ~34K + drain pads <54K)
#define SCAP 24          // staged entries per bucket; flush groups of 16 (64B)
#define SPITCH 25        // odd pitch -> bank-conflict-free across buckets
#define PA_BLOCKS 1280   // 5 blocks/CU (LDS ~31.6KB/block)
#define PA_THREADS 256
#define PB_BLOCKS 128
#define PB_THREADS 512
#define SENTINEL 0xFFFFFFFFu

// ---------------------------------------------------------------------------
// E = concat(U_emb, V_emb), vectorized float4
// ---------------------------------------------------------------------------
__global__ __launch_bounds__(256) void init_e_kernel(
    const float* __restrict__ U, const float* __restrict__ V,
    float* __restrict__ E, int nU_elems, int total_elems) {
  int i = (blockIdx.x * blockDim.x + threadIdx.x) * 4;
  if (i >= total_elems) return;
  float4 v = (i < nU_elems)
      ? *reinterpret_cast<const float4*>(U + i)
      : *reinterpret_cast<const float4*>(V + (i - nU_elems));
  *reinterpret_cast<float4*>(E + i) = v;
}

// ---------------------------------------------------------------------------
// Pass A: LDS-staged multisplit of packed (row_low<<19 | col) 4B entries into
// fixed-capacity row-range buckets (base = b*BCAP).
// Flush quantum = 16 entries = one full 64B line at an aligned offset.
// ---------------------------------------------------------------------------
__global__ __launch_bounds__(PA_THREADS) void pass_a_kernel(
    const int* __restrict__ rows, const int* __restrict__ cols,
    unsigned* __restrict__ temp, int* __restrict__ gcur, int nnz, int nb) {
  __shared__ unsigned stage[NB_MAX * SPITCH];
  __shared__ int scnt[NB_MAX];
  for (int b = threadIdx.x; b < nb; b += PA_THREADS) scnt[b] = 0;
  __syncthreads();

  int epb = (nnz + PA_BLOCKS - 1) / PA_BLOCKS;
  int cstart = blockIdx.x * epb;
  int cend = min(nnz, cstart + epb);

  for (int base = cstart; base < cend; base += PA_THREADS) {
    int e = base + threadIdx.x;
    bool done = (e >= cend);
    unsigned packed = 0;
    int b = 0;
    if (!done) {
      int r = rows[e];
      int c = cols[e];
      b = r >> BSHIFT;
      packed = ((unsigned)(r & (BROWS - 1)) << 19) | (unsigned)c;
    }
    for (;;) {
      if (!done) {
        int idx = atomicAdd(&scnt[b], 1);
        if (idx < SCAP) {
          stage[b * SPITCH + idx] = packed;
          done = true;
        } else {
          atomicAdd(&scnt[b], -1);  // undo failed claim; retry after flush
        }
      }
      __syncthreads();
      // flush full 16-groups (one thread per bucket, conflict-free pitch)
      for (int bb = threadIdx.x; bb < nb; bb += PA_THREADS) {
        int cval = scnt[bb];
        if (cval >= 16) {
          int pos = atomicAdd(&gcur[bb], 16);
          unsigned v[16];
#pragma unroll
          for (int k = 0; k < 16; ++k) v[k] = stage[bb * SPITCH + k];
          uint4* dst = reinterpret_cast<uint4*>(&temp[pos]);
          dst[0] = make_uint4(v[0], v[1], v[2], v[3]);
          dst[1] = make_uint4(v[4], v[5], v[6], v[7]);
          dst[2] = make_uint4(v[8], v[9], v[10], v[11]);
          dst[3] = make_uint4(v[12], v[13], v[14], v[15]);
          for (int k = 0; k < cval - 16; ++k)
            stage[bb * SPITCH + k] = stage[bb * SPITCH + 16 + k];
          scnt[bb] = cval - 16;
        }
      }
      int pend = __syncthreads_count(done ? 0 : 1);
      if (pend == 0) break;
    }
  }
  // final drain: pad residue to a full aligned 16-group with sentinels
  __syncthreads();
  for (int bb = threadIdx.x; bb < nb; bb += PA_THREADS) {
    int cval = scnt[bb];
    if (cval > 0) {
      int pos = atomicAdd(&gcur[bb], 16);
      for (int k = 0; k < 16; ++k)
        temp[pos + k] = (k < cval) ? stage[bb * SPITCH + k] : SENTINEL;
    }
  }
}

// ---------------------------------------------------------------------------
// Per-bucket histogram: LDS atomics + coalesced contiguous cnt stores.
// ---------------------------------------------------------------------------
__global__ __launch_bounds__(512) void hist_bucket_kernel(
    const unsigned* __restrict__ temp, const int* __restrict__ gcur,
    int* __restrict__ cnt, int n) {
  __shared__ int lcnt[BROWS];
  int b = blockIdx.x;
  int base_row = b << BSHIFT;
  int nrows = min(BROWS, n - base_row);
  for (int r = threadIdx.x; r < BROWS; r += 512) lcnt[r] = 0;
  __syncthreads();
  int start = b * BCAP, end = gcur[b];
  for (int i = start + threadIdx.x; i < end; i += 512) {
    unsigned ent = temp[i];
    if (ent != SENTINEL) atomicAdd(&lcnt[ent >> 19], 1);
  }
  __syncthreads();
  for (int r = threadIdx.x; r < nrows; r += 512)
    cnt[base_row + r] = lcnt[r];
}

// phase1: per-block chunk reduction
__global__ __launch_bounds__(256) void scan_phase1(
    const int* __restrict__ cnt, int* __restrict__ block_sums, int n) {
  __shared__ int sdata[256];
  int base = blockIdx.x * SCAN_CHUNK;
  int sum = 0;
#pragma unroll
  for (int k = 0; k < 8; ++k) {
    int idx = base + k * 256 + threadIdx.x;
    if (idx < n) sum += cnt[idx];
  }
  sdata[threadIdx.x] = sum;
  __syncthreads();
  for (int s = 128; s > 0; s >>= 1) {
    if (threadIdx.x < s) sdata[threadIdx.x] += sdata[threadIdx.x + s];
    __syncthreads();
  }
  if (threadIdx.x == 0) block_sums[blockIdx.x] = sdata[0];
}

// phase2: single 256-wide exclusive scan over block sums; writes row_ptr[n]
__global__ __launch_bounds__(256) void scan_phase2(
    int* __restrict__ block_sums, int n_blocks, int* __restrict__ row_ptr, int n) {
  __shared__ int tmp[256];
  int v = (threadIdx.x < n_blocks) ? block_sums[threadIdx.x] : 0;
  tmp[threadIdx.x] = v;
  __syncthreads();
  for (int offs = 1; offs < 256; offs <<= 1) {
    int t = (threadIdx.x >= offs) ? tmp[threadIdx.x - offs] : 0;
    __syncthreads();
    tmp[threadIdx.x] += t;
    __syncthreads();
  }
  if (threadIdx.x < n_blocks) block_sums[threadIdx.x] = tmp[threadIdx.x] - v;
  if (threadIdx.x == 0) row_ptr[n] = tmp[255];
}

// phase3: per-block chunk scan with offset, writes row_ptr
__global__ __launch_bounds__(256) void scan_phase3(
    const int* __restrict__ cnt, const int* __restrict__ block_sums,
    int* __restrict__ row_ptr, int n) {
  __shared__ int tmp[256];
  __shared__ int s_carry;
  int base = blockIdx.x * SCAN_CHUNK;
  if (threadIdx.x == 0) s_carry = block_sums[blockIdx.x];
  __syncthreads();
#pragma unroll 1
  for (int k = 0; k < 8; ++k) {
    int idx = base + k * 256 + threadIdx.x;
    int v = (idx < n) ? cnt[idx] : 0;
    tmp[threadIdx.x] = v;
    __syncthreads();
    for (int offs = 1; offs < 256; offs <<= 1) {
      int t = (threadIdx.x >= offs) ? tmp[threadIdx.x - offs] : 0;
      __syncthreads();
      tmp[threadIdx.x] += t;
      __syncthreads();
    }
    int incl = tmp[threadIdx.x];
    int carry = s_carry;
    if (idx < n) row_ptr[idx] = carry + incl - v;
    __syncthreads();
    if (threadIdx.x == 0) s_carry = carry + tmp[255];
    __syncthreads();
  }
}

// rs[i] = 1/sqrt(deg[i]); deg==0 -> 1
__global__ __launch_bounds__(256) void rs_kernel(
    const int* __restrict__ cnt, float* __restrict__ rs, int n) {
  int i = blockIdx.x * blockDim.x + threadIdx.x;
  if (i < n) {
    float d = (float)cnt[i];
    rs[i] = (d > 0.0f) ? 1.0f / sqrtf(d) : 1.0f;
  }
}

// gcur init for fixed-capacity buckets
__global__ __launch_bounds__(256) void bucket_init_kernel(
    int* __restrict__ gcur, int nb) {
  int b = blockIdx.x * blockDim.x + threadIdx.x;
  if (b < nb) gcur[b] = b * BCAP;
}

// ---------------------------------------------------------------------------
// Pass B: per bucket, scatter bucket entries to exact CSR positions.
// ---------------------------------------------------------------------------
__global__ __launch_bounds__(PB_THREADS) void pass_b_kernel(
    const unsigned* __restrict__ temp, const int* __restrict__ gcur,
    const int* __restrict__ row_ptr, const float* __restrict__ rs,
    int2* __restrict__ csr_cv, int nb, int n) {
  __shared__ int ldscur[BROWS];
  for (int b = blockIdx.x; b < nb; b += gridDim.x) {
    int base_row = b << BSHIFT;
    int nrows = min(BROWS, n - base_row);
    for (int r = threadIdx.x; r < nrows; r += PB_THREADS)
      ldscur[r] = row_ptr[base_row + r];
    __syncthreads();
    int start = b * BCAP, end = gcur[b];
    for (int i = start + threadIdx.x; i < end; i += PB_THREADS) {
      unsigned ent = temp[i];
      if (ent != SENTINEL) {
        int col = (int)(ent & 0x7FFFFu);
        int rlow = (int)(ent >> 19);
        int p = atomicAdd(&ldscur[rlow], 1);
        float val = rs[base_row + rlow] * rs[col];
        csr_cv[p] = make_int2(col, __float_as_int(val));
      }
    }
    __syncthreads();
  }
}

// ---------------------------------------------------------------------------
// SpMM: one wave per row; the wave's two 32-lane halves process two edges per
// memory instruction (each half gathers a different column's row as float2),
// doubling the random-line requests in flight per issue slot. Halves are
// combined at the end with one xor-32 shuffle.
// ---------------------------------------------------------------------------
__global__ __launch_bounds__(256) void spmm_kernel(
    const int* __restrict__ row_ptr, const int2* __restrict__ csr_cv,
    const float2* __restrict__ cur2, float2* __restrict__ next2, int n_rows) {
  int row  = blockIdx.x * (blockDim.x >> 6) + (threadIdx.x >> 6);
  int lane = threadIdx.x & 63;
  int half = lane >> 5;   // which edge of the pair this lane works on
  int sub  = lane & 31;   // float2 index within the gathered row
  if (row >= n_rows) return;
  int start = row_ptr[row];
  int end   = row_ptr[row + 1];
  float2 acc = make_float2(0.0f, 0.0f);
  int e = start;
  for (; e + 8 <= end; e += 8) {
    int2 ed0 = csr_cv[e     + half];
    int2 ed1 = csr_cv[e + 2 + half];
    int2 ed2 = csr_cv[e + 4 + half];
    int2 ed3 = csr_cv[e + 6 + half];
    float2 g0 = cur2[ed0.x * 32 + sub];
    float2 g1 = cur2[ed1.x * 32 + sub];
    float2 g2 = cur2[ed2.x * 32 + sub];
    float2 g3 = cur2[ed3.x * 32 + sub];
    float v0 = __int_as_float(ed0.y), v1 = __int_as_float(ed1.y);
    float v2 = __int_as_float(ed2.y), v3 = __int_as_float(ed3.y);
    acc.x = fmaf(v0, g0.x, acc.x); acc.y = fmaf(v0, g0.y, acc.y);
    acc.x = fmaf(v1, g1.x, acc.x); acc.y = fmaf(v1, g1.y, acc.y);
    acc.x = fmaf(v2, g2.x, acc.x); acc.y = fmaf(v2, g2.y, acc.y);
    acc.x = fmaf(v3, g3.x, acc.x); acc.y = fmaf(v3, g3.y, acc.y);
  }
  for (; e + 2 <= end; e += 2) {
    int2 ed = csr_cv[e + half];
    float2 g = cur2[ed.x * 32 + sub];
    float v = __int_as_float(ed.y);
    acc.x = fmaf(v, g.x, acc.x); acc.y = fmaf(v, g.y, acc.y);
  }
  if (e < end) {  // odd final edge: both halves load it, half 1 weights by 0
    int2 ed = csr_cv[e];
    float2 g = cur2[ed.x * 32 + sub];
    float v = half ? 0.0f : __int_as_float(ed.y);
    acc.x = fmaf(v, g.x, acc.x); acc.y = fmaf(v, g.y, acc.y);
  }
  // combine the two half-wave partial sums (even edges + odd edges)
  acc.x += __shfl_xor(acc.x, 32, 64);
  acc.y += __shfl_xor(acc.y, 32, 64);
  if (half == 0) next2[row * 32 + sub] = acc;
}

// ---------------------------------------------------------------------------
__global__ __launch_bounds__(256) void gather_kernel(
    const int* __restrict__ u, const int* __restrict__ it,
    const float* __restrict__ cur, float* __restrict__ accU,
    float* __restrict__ accI, int batch, int nU) {
  int b    = blockIdx.x * (blockDim.x >> 6) + (threadIdx.x >> 6);
  int lane = threadIdx.x & 63;
  if (b >= batch) return;
  accU[b * DIMS + lane] += cur[u[b] * DIMS + lane];
  accI[b * DIMS + lane] += cur[(it[b] + nU) * DIMS + lane];
}

__global__ __launch_bounds__(256) void score_kernel(
    const float* __restrict__ accU, const float* __restrict__ accI,
    float* __restrict__ out, int batch) {
  int b    = blockIdx.x * (blockDim.x >> 6) + (threadIdx.x >> 6);
  int lane = threadIdx.x & 63;
  if (b >= batch) return;
  float v = accU[b * DIMS + lane] * accI[b * DIMS + lane];
  for (int offs = 32; offs > 0; offs >>= 1) v += __shfl_down(v, offs, 64);
  if (lane == 0) out[b] = v * (1.0f / 16.0f);
}

// ---------------------------------------------------------------------------
extern "C" void kernel_launch(void* const* d_in, const int* in_sizes, int n_in,
                              void* d_out, int out_size, void* d_ws, size_t ws_size,
                              hipStream_t stream) {
  const int*   u     = (const int*)d_in[0];
  const int*   it    = (const int*)d_in[1];
  const int*   arows = (const int*)d_in[2];
  const int*   acols = (const int*)d_in[3];
  const float* U     = (const float*)d_in[5];
  const float* V     = (const float*)d_in[6];

  const int batch = in_sizes[0];
  const int nnz   = in_sizes[2];
  const int nU    = in_sizes[5] / DIMS;
  const int nV    = in_sizes[6] / DIMS;
  const int N     = nU + nV;
  const int n_scan_blocks = (N + SCAN_CHUNK - 1) / SCAN_CHUNK;
  const int NB    = (N + BROWS - 1) >> BSHIFT;  // 293
  const size_t ebytes = (size_t)N * DIMS * 4;
  const size_t tbytes = (size_t)NB * BCAP * 4;
  const size_t xbytes = tbytes > ebytes ? tbytes : ebytes;

  char*  ws  = (char*)d_ws;
  size_t off = 0;
  auto take = [&](size_t bytes) -> void* {
    void* p = ws + off;
    off = (off + bytes + 255) & ~(size_t)255;
    return p;
  };
  int*     cnt        = (int*)take((size_t)N * 4);
  float*   rs         = (float*)take((size_t)N * 4);
  int*     row_ptr    = (int*)take((size_t)(N + 1) * 4);
  int*     block_sums = (int*)take((size_t)256 * 4);
  int*     gcur       = (int*)take((size_t)NB * 4);
  int2*    csr_cv     = (int2*)take((size_t)nnz * 8);
  char*    X          = (char*)take(xbytes);   // temp (build), then bufA (E)
  float*   bufB       = (float*)take(ebytes);
  float*   accU       = (float*)take((size_t)batch * DIMS * 4);
  float*   accI       = (float*)take((size_t)batch * DIMS * 4);
  unsigned* temp      = (unsigned*)X;
  float*   bufA       = (float*)X;

  hipMemsetAsync(accU, 0, (size_t)batch * DIMS * 4, stream);
  hipMemsetAsync(accI, 0, (size_t)batch * DIMS * 4, stream);

  // ---- CSR build (uses X as temp) ----
  bucket_init_kernel<<<(NB + 255) / 256, 256, 0, stream>>>(gcur, NB);
  pass_a_kernel<<<PA_BLOCKS, PA_THREADS, 0, stream>>>(arows, acols, temp, gcur, nnz, NB);
  hist_bucket_kernel<<<NB, 512, 0, stream>>>(temp, gcur, cnt, N);
  scan_phase1<<<n_scan_blocks, 256, 0, stream>>>(cnt, block_sums, N);
  scan_phase2<<<1, 256, 0, stream>>>(block_sums, n_scan_blocks, row_ptr, N);
  scan_phase3<<<n_scan_blocks, 256, 0, stream>>>(cnt, block_sums, row_ptr, N);
  rs_kernel<<<(N + 255) / 256, 256, 0, stream>>>(cnt, rs, N);
  pass_b_kernel<<<PB_BLOCKS, PB_THREADS, 0, stream>>>(temp, gcur, row_ptr, rs,
                                                      csr_cv, NB, N);

  // ---- E0 init (X becomes bufA now that temp is dead) ----
  {
    int total = N * DIMS;
    int t4 = total / 4;
    init_e_kernel<<<(t4 + 255) / 256, 256, 0, stream>>>(U, V, bufA, nU * DIMS, total);
  }
  gather_kernel<<<(batch + 3) / 4, 256, 0, stream>>>(u, it, bufA, accU, accI, batch, nU);

  float* cur = bufA;
  float* nxt = bufB;
  for (int layer = 0; layer < 3; ++layer) {
    spmm_kernel<<<(N + 3) / 4, 256, 0, stream>>>(row_ptr, csr_cv,
                                                 (const float2*)cur, (float2*)nxt, N);
    gather_kernel<<<(batch + 3) / 4, 256, 0, stream>>>(u, it, nxt, accU, accI, batch, nU);
    float* t = cur; cur = nxt; nxt = t;
  }

  score_kernel<<<(batch + 3) / 4, 256, 0, stream>>>(accU, accI, (float*)d_out, batch);
}

// Round 8
// 1800.833 us; speedup vs baseline: 1.3708x; 1.0053x over previous
//
#include <hip/hip_runtime.h>

#define DIMS 64
#define SCAN_CHUNK 2048  // 256 threads * 8 elems
#define BSHIFT 10        // 1024 rows per bucket
#define BROWS (1 << BSHIFT)
#define NB_MAX 304       // >= ceil(300K/1024)=293
#define BCAP 65536       // fixed bucket capacity (mean ~34K + drain pads <54K)
#define SCAP 24          // staged entries per bucket; flush groups of 16 (64B)
#define SPITCH 25        // odd pitch -> bank-conflict-free across buckets
#define PA_BLOCKS 1280   // 5 blocks/CU (LDS ~31.6KB/block)
#define PA_THREADS 256
#define PB_BLOCKS 128
#define PB_THREADS 512
#define SENTINEL 0xFFFFFFFFu

// nt 8B load of an int2 (edge record): keep the 80MB/layer CSR stream from
// polluting L2/L3, which should stay dedicated to the hot 77MB gather target
__device__ __forceinline__ int2 ld_nt_int2(const int2* p) {
  unsigned long long v =
      __builtin_nontemporal_load(reinterpret_cast<const unsigned long long*>(p));
  int2 r;
  r.x = (int)(unsigned)(v & 0xFFFFFFFFull);
  r.y = (int)(unsigned)(v >> 32);
  return r;
}

// ---------------------------------------------------------------------------
// E = concat(U_emb, V_emb), vectorized float4
// ---------------------------------------------------------------------------
__global__ __launch_bounds__(256) void init_e_kernel(
    const float* __restrict__ U, const float* __restrict__ V,
    float* __restrict__ E, int nU_elems, int total_elems) {
  int i = (blockIdx.x * blockDim.x + threadIdx.x) * 4;
  if (i >= total_elems) return;
  float4 v = (i < nU_elems)
      ? *reinterpret_cast<const float4*>(U + i)
      : *reinterpret_cast<const float4*>(V + (i - nU_elems));
  *reinterpret_cast<float4*>(E + i) = v;
}

// ---------------------------------------------------------------------------
// Pass A: LDS-staged multisplit of packed (row_low<<19 | col) 4B entries into
// fixed-capacity row-range buckets (base = b*BCAP).
// Flush quantum = 16 entries = one full 64B line at an aligned offset.
// ---------------------------------------------------------------------------
__global__ __launch_bounds__(PA_THREADS) void pass_a_kernel(
    const int* __restrict__ rows, const int* __restrict__ cols,
    unsigned* __restrict__ temp, int* __restrict__ gcur, int nnz, int nb) {
  __shared__ unsigned stage[NB_MAX * SPITCH];
  __shared__ int scnt[NB_MAX];
  for (int b = threadIdx.x; b < nb; b += PA_THREADS) scnt[b] = 0;
  __syncthreads();

  int epb = (nnz + PA_BLOCKS - 1) / PA_BLOCKS;
  int cstart = blockIdx.x * epb;
  int cend = min(nnz, cstart + epb);

  for (int base = cstart; base < cend; base += PA_THREADS) {
    int e = base + threadIdx.x;
    bool done = (e >= cend);
    unsigned packed = 0;
    int b = 0;
    if (!done) {
      int r = rows[e];
      int c = cols[e];
      b = r >> BSHIFT;
      packed = ((unsigned)(r & (BROWS - 1)) << 19) | (unsigned)c;
    }
    for (;;) {
      if (!done) {
        int idx = atomicAdd(&scnt[b], 1);
        if (idx < SCAP) {
          stage[b * SPITCH + idx] = packed;
          done = true;
        } else {
          atomicAdd(&scnt[b], -1);  // undo failed claim; retry after flush
        }
      }
      __syncthreads();
      // flush full 16-groups (one thread per bucket, conflict-free pitch)
      for (int bb = threadIdx.x; bb < nb; bb += PA_THREADS) {
        int cval = scnt[bb];
        if (cval >= 16) {
          int pos = atomicAdd(&gcur[bb], 16);
          unsigned v[16];
#pragma unroll
          for (int k = 0; k < 16; ++k) v[k] = stage[bb * SPITCH + k];
          uint4* dst = reinterpret_cast<uint4*>(&temp[pos]);
          dst[0] = make_uint4(v[0], v[1], v[2], v[3]);
          dst[1] = make_uint4(v[4], v[5], v[6], v[7]);
          dst[2] = make_uint4(v[8], v[9], v[10], v[11]);
          dst[3] = make_uint4(v[12], v[13], v[14], v[15]);
          for (int k = 0; k < cval - 16; ++k)
            stage[bb * SPITCH + k] = stage[bb * SPITCH + 16 + k];
          scnt[bb] = cval - 16;
        }
      }
      int pend = __syncthreads_count(done ? 0 : 1);
      if (pend == 0) break;
    }
  }
  // final drain: pad residue to a full aligned 16-group with sentinels
  __syncthreads();
  for (int bb = threadIdx.x; bb < nb; bb += PA_THREADS) {
    int cval = scnt[bb];
    if (cval > 0) {
      int pos = atomicAdd(&gcur[bb], 16);
      for (int k = 0; k < 16; ++k)
        temp[pos + k] = (k < cval) ? stage[bb * SPITCH + k] : SENTINEL;
    }
  }
}

// ---------------------------------------------------------------------------
// Per-bucket histogram: LDS atomics + coalesced contiguous cnt stores.
// ---------------------------------------------------------------------------
__global__ __launch_bounds__(512) void hist_bucket_kernel(
    const unsigned* __restrict__ temp, const int* __restrict__ gcur,
    int* __restrict__ cnt, int n) {
  __shared__ int lcnt[BROWS];
  int b = blockIdx.x;
  int base_row = b << BSHIFT;
  int nrows = min(BROWS, n - base_row);
  for (int r = threadIdx.x; r < BROWS; r += 512) lcnt[r] = 0;
  __syncthreads();
  int start = b * BCAP, end = gcur[b];
  for (int i = start + threadIdx.x; i < end; i += 512) {
    unsigned ent = temp[i];
    if (ent != SENTINEL) atomicAdd(&lcnt[ent >> 19], 1);
  }
  __syncthreads();
  for (int r = threadIdx.x; r < nrows; r += 512)
    cnt[base_row + r] = lcnt[r];
}

// phase1: per-block chunk reduction
__global__ __launch_bounds__(256) void scan_phase1(
    const int* __restrict__ cnt, int* __restrict__ block_sums, int n) {
  __shared__ int sdata[256];
  int base = blockIdx.x * SCAN_CHUNK;
  int sum = 0;
#pragma unroll
  for (int k = 0; k < 8; ++k) {
    int idx = base + k * 256 + threadIdx.x;
    if (idx < n) sum += cnt[idx];
  }
  sdata[threadIdx.x] = sum;
  __syncthreads();
  for (int s = 128; s > 0; s >>= 1) {
    if (threadIdx.x < s) sdata[threadIdx.x] += sdata[threadIdx.x + s];
    __syncthreads();
  }
  if (threadIdx.x == 0) block_sums[blockIdx.x] = sdata[0];
}

// phase2: single 256-wide exclusive scan over block sums; writes row_ptr[n]
__global__ __launch_bounds__(256) void scan_phase2(
    int* __restrict__ block_sums, int n_blocks, int* __restrict__ row_ptr, int n) {
  __shared__ int tmp[256];
  int v = (threadIdx.x < n_blocks) ? block_sums[threadIdx.x] : 0;
  tmp[threadIdx.x] = v;
  __syncthreads();
  for (int offs = 1; offs < 256; offs <<= 1) {
    int t = (threadIdx.x >= offs) ? tmp[threadIdx.x - offs] : 0;
    __syncthreads();
    tmp[threadIdx.x] += t;
    __syncthreads();
  }
  if (threadIdx.x < n_blocks) block_sums[threadIdx.x] = tmp[threadIdx.x] - v;
  if (threadIdx.x == 0) row_ptr[n] = tmp[255];
}

// phase3: per-block chunk scan with offset, writes row_ptr
__global__ __launch_bounds__(256) void scan_phase3(
    const int* __restrict__ cnt, const int* __restrict__ block_sums,
    int* __restrict__ row_ptr, int n) {
  __shared__ int tmp[256];
  __shared__ int s_carry;
  int base = blockIdx.x * SCAN_CHUNK;
  if (threadIdx.x == 0) s_carry = block_sums[blockIdx.x];
  __syncthreads();
#pragma unroll 1
  for (int k = 0; k < 8; ++k) {
    int idx = base + k * 256 + threadIdx.x;
    int v = (idx < n) ? cnt[idx] : 0;
    tmp[threadIdx.x] = v;
    __syncthreads();
    for (int offs = 1; offs < 256; offs <<= 1) {
      int t = (threadIdx.x >= offs) ? tmp[threadIdx.x - offs] : 0;
      __syncthreads();
      tmp[threadIdx.x] += t;
      __syncthreads();
    }
    int incl = tmp[threadIdx.x];
    int carry = s_carry;
    if (idx < n) row_ptr[idx] = carry + incl - v;
    __syncthreads();
    if (threadIdx.x == 0) s_carry = carry + tmp[255];
    __syncthreads();
  }
}

// rs[i] = 1/sqrt(deg[i]); deg==0 -> 1
__global__ __launch_bounds__(256) void rs_kernel(
    const int* __restrict__ cnt, float* __restrict__ rs, int n) {
  int i = blockIdx.x * blockDim.x + threadIdx.x;
  if (i < n) {
    float d = (float)cnt[i];
    rs[i] = (d > 0.0f) ? 1.0f / sqrtf(d) : 1.0f;
  }
}

// gcur init for fixed-capacity buckets
__global__ __launch_bounds__(256) void bucket_init_kernel(
    int* __restrict__ gcur, int nb) {
  int b = blockIdx.x * blockDim.x + threadIdx.x;
  if (b < nb) gcur[b] = b * BCAP;
}

// ---------------------------------------------------------------------------
// Pass B: per bucket, scatter bucket entries to exact CSR positions.
// ---------------------------------------------------------------------------
__global__ __launch_bounds__(PB_THREADS) void pass_b_kernel(
    const unsigned* __restrict__ temp, const int* __restrict__ gcur,
    const int* __restrict__ row_ptr, const float* __restrict__ rs,
    int2* __restrict__ csr_cv, int nb, int n) {
  __shared__ int ldscur[BROWS];
  for (int b = blockIdx.x; b < nb; b += gridDim.x) {
    int base_row = b << BSHIFT;
    int nrows = min(BROWS, n - base_row);
    for (int r = threadIdx.x; r < nrows; r += PB_THREADS)
      ldscur[r] = row_ptr[base_row + r];
    __syncthreads();
    int start = b * BCAP, end = gcur[b];
    for (int i = start + threadIdx.x; i < end; i += PB_THREADS) {
      unsigned ent = temp[i];
      if (ent != SENTINEL) {
        int col = (int)(ent & 0x7FFFFu);
        int rlow = (int)(ent >> 19);
        int p = atomicAdd(&ldscur[rlow], 1);
        float val = rs[base_row + rlow] * rs[col];
        csr_cv[p] = make_int2(col, __float_as_int(val));
      }
    }
    __syncthreads();
  }
}

// ---------------------------------------------------------------------------
// SpMM: one wave per row; the wave's four 16-lane quarters each gather a
// different edge's row as float4 (4 edges x 256B = 1KB per instruction),
// unrolled 4 deep -> 16 edges / 4KB outstanding per wave. Edge records are
// nt-loaded (stream, no cache allocation). Quarters combined with two
// xor-shuffles; quarter 0 stores the 256B output row.
// ---------------------------------------------------------------------------
__global__ __launch_bounds__(256) void spmm_kernel(
    const int* __restrict__ row_ptr, const int2* __restrict__ csr_cv,
    const float4* __restrict__ cur4, float4* __restrict__ next4, int n_rows) {
  int row  = blockIdx.x * (blockDim.x >> 6) + (threadIdx.x >> 6);
  int lane = threadIdx.x & 63;
  int q    = lane >> 4;   // quarter: which edge of the group of 4
  int sub  = lane & 15;   // float4 index within the gathered row
  if (row >= n_rows) return;
  int start = row_ptr[row];
  int end   = row_ptr[row + 1];
  float4 acc = make_float4(0.0f, 0.0f, 0.0f, 0.0f);
  int e = start;
  for (; e + 16 <= end; e += 16) {
    int2 ed0 = ld_nt_int2(&csr_cv[e      + q]);
    int2 ed1 = ld_nt_int2(&csr_cv[e + 4  + q]);
    int2 ed2 = ld_nt_int2(&csr_cv[e + 8  + q]);
    int2 ed3 = ld_nt_int2(&csr_cv[e + 12 + q]);
    float4 g0 = cur4[ed0.x * 16 + sub];
    float4 g1 = cur4[ed1.x * 16 + sub];
    float4 g2 = cur4[ed2.x * 16 + sub];
    float4 g3 = cur4[ed3.x * 16 + sub];
    float v0 = __int_as_float(ed0.y), v1 = __int_as_float(ed1.y);
    float v2 = __int_as_float(ed2.y), v3 = __int_as_float(ed3.y);
    acc.x = fmaf(v0, g0.x, acc.x); acc.y = fmaf(v0, g0.y, acc.y);
    acc.z = fmaf(v0, g0.z, acc.z); acc.w = fmaf(v0, g0.w, acc.w);
    acc.x = fmaf(v1, g1.x, acc.x); acc.y = fmaf(v1, g1.y, acc.y);
    acc.z = fmaf(v1, g1.z, acc.z); acc.w = fmaf(v1, g1.w, acc.w);
    acc.x = fmaf(v2, g2.x, acc.x); acc.y = fmaf(v2, g2.y, acc.y);
    acc.z = fmaf(v2, g2.z, acc.z); acc.w = fmaf(v2, g2.w, acc.w);
    acc.x = fmaf(v3, g3.x, acc.x); acc.y = fmaf(v3, g3.y, acc.y);
    acc.z = fmaf(v3, g3.z, acc.z); acc.w = fmaf(v3, g3.w, acc.w);
  }
  for (; e + 4 <= end; e += 4) {
    int2 ed = ld_nt_int2(&csr_cv[e + q]);
    float4 g = cur4[ed.x * 16 + sub];
    float v = __int_as_float(ed.y);
    acc.x = fmaf(v, g.x, acc.x); acc.y = fmaf(v, g.y, acc.y);
    acc.z = fmaf(v, g.z, acc.z); acc.w = fmaf(v, g.w, acc.w);
  }
  if (e < end) {  // 1..3 remaining: masked quarters (inactive quarters w=0)
    int idx = min(e + q, end - 1);
    int2 ed = ld_nt_int2(&csr_cv[idx]);
    float4 g = cur4[ed.x * 16 + sub];
    float v = (e + q < end) ? __int_as_float(ed.y) : 0.0f;
    acc.x = fmaf(v, g.x, acc.x); acc.y = fmaf(v, g.y, acc.y);
    acc.z = fmaf(v, g.z, acc.z); acc.w = fmaf(v, g.w, acc.w);
  }
  // combine the four quarter partial sums
#pragma unroll
  for (int offs = 16; offs <= 32; offs <<= 1) {
    acc.x += __shfl_xor(acc.x, offs, 64);
    acc.y += __shfl_xor(acc.y, offs, 64);
    acc.z += __shfl_xor(acc.z, offs, 64);
    acc.w += __shfl_xor(acc.w, offs, 64);
  }
  if (q == 0) next4[row * 16 + sub] = acc;
}

// ---------------------------------------------------------------------------
__global__ __launch_bounds__(256) void gather_kernel(
    const int* __restrict__ u, const int* __restrict__ it,
    const float* __restrict__ cur, float* __restrict__ accU,
    float* __restrict__ accI, int batch, int nU) {
  int b    = blockIdx.x * (blockDim.x >> 6) + (threadIdx.x >> 6);
  int lane = threadIdx.x & 63;
  if (b >= batch) return;
  accU[b * DIMS + lane] += cur[u[b] * DIMS + lane];
  accI[b * DIMS + lane] += cur[(it[b] + nU) * DIMS + lane];
}

__global__ __launch_bounds__(256) void score_kernel(
    const float* __restrict__ accU, const float* __restrict__ accI,
    float* __restrict__ out, int batch) {
  int b    = blockIdx.x * (blockDim.x >> 6) + (threadIdx.x >> 6);
  int lane = threadIdx.x & 63;
  if (b >= batch) return;
  float v = accU[b * DIMS + lane] * accI[b * DIMS + lane];
  for (int offs = 32; offs > 0; offs >>= 1) v += __shfl_down(v, offs, 64);
  if (lane == 0) out[b] = v * (1.0f / 16.0f);
}

// ---------------------------------------------------------------------------
extern "C" void kernel_launch(void* const* d_in, const int* in_sizes, int n_in,
                              void* d_out, int out_size, void* d_ws, size_t ws_size,
                              hipStream_t stream) {
  const int*   u     = (const int*)d_in[0];
  const int*   it    = (const int*)d_in[1];
  const int*   arows = (const int*)d_in[2];
  const int*   acols = (const int*)d_in[3];
  const float* U     = (const float*)d_in[5];
  const float* V     = (const float*)d_in[6];

  const int batch = in_sizes[0];
  const int nnz   = in_sizes[2];
  const int nU    = in_sizes[5] / DIMS;
  const int nV    = in_sizes[6] / DIMS;
  const int N     = nU + nV;
  const int n_scan_blocks = (N + SCAN_CHUNK - 1) / SCAN_CHUNK;
  const int NB    = (N + BROWS - 1) >> BSHIFT;  // 293
  const size_t ebytes = (size_t)N * DIMS * 4;
  const size_t tbytes = (size_t)NB * BCAP * 4;
  const size_t xbytes = tbytes > ebytes ? tbytes : ebytes;

  char*  ws  = (char*)d_ws;
  size_t off = 0;
  auto take = [&](size_t bytes) -> void* {
    void* p = ws + off;
    off = (off + bytes + 255) & ~(size_t)255;
    return p;
  };
  int*     cnt        = (int*)take((size_t)N * 4);
  float*   rs         = (float*)take((size_t)N * 4);
  int*     row_ptr    = (int*)take((size_t)(N + 1) * 4);
  int*     block_sums = (int*)take((size_t)256 * 4);
  int*     gcur       = (int*)take((size_t)NB * 4);
  int2*    csr_cv     = (int2*)take((size_t)nnz * 8);
  char*    X          = (char*)take(xbytes);   // temp (build), then bufA (E)
  float*   bufB       = (float*)take(ebytes);
  float*   accU       = (float*)take((size_t)batch * DIMS * 4);
  float*   accI       = (float*)take((size_t)batch * DIMS * 4);
  unsigned* temp      = (unsigned*)X;
  float*   bufA       = (float*)X;

  hipMemsetAsync(accU, 0, (size_t)batch * DIMS * 4, stream);
  hipMemsetAsync(accI, 0, (size_t)batch * DIMS * 4, stream);

  // ---- CSR build (uses X as temp) ----
  bucket_init_kernel<<<(NB + 255) / 256, 256, 0, stream>>>(gcur, NB);
  pass_a_kernel<<<PA_BLOCKS, PA_THREADS, 0, stream>>>(arows, acols, temp, gcur, nnz, NB);
  hist_bucket_kernel<<<NB, 512, 0, stream>>>(temp, gcur, cnt, N);
  scan_phase1<<<n_scan_blocks, 256, 0, stream>>>(cnt, block_sums, N);
  scan_phase2<<<1, 256, 0, stream>>>(block_sums, n_scan_blocks, row_ptr, N);
  scan_phase3<<<n_scan_blocks, 256, 0, stream>>>(cnt, block_sums, row_ptr, N);
  rs_kernel<<<(N + 255) / 256, 256, 0, stream>>>(cnt, rs, N);
  pass_b_kernel<<<PB_BLOCKS, PB_THREADS, 0, stream>>>(temp, gcur, row_ptr, rs,
                                                      csr_cv, NB, N);

  // ---- E0 init (X becomes bufA now that temp is dead) ----
  {
    int total = N * DIMS;
    int t4 = total / 4;
    init_e_kernel<<<(t4 + 255) / 256, 256, 0, stream>>>(U, V, bufA, nU * DIMS, total);
  }
  gather_kernel<<<(batch + 3) / 4, 256, 0, stream>>>(u, it, bufA, accU, accI, batch, nU);

  float* cur = bufA;
  float* nxt = bufB;
  for (int layer = 0; layer < 3; ++layer) {
    spmm_kernel<<<(N + 3) / 4, 256, 0, stream>>>(row_ptr, csr_cv,
                                                 (const float4*)cur, (float4*)nxt, N);
    gather_kernel<<<(batch + 3) / 4, 256, 0, stream>>>(u, it, nxt, accU, accI, batch, nU);
    float* t = cur; cur = nxt; nxt = t;
  }

  score_kernel<<<(batch + 3) / 4, 256, 0, stream>>>(accU, accI, (float*)d_out, batch);
}